// Round 1
// 175.411 us; speedup vs baseline: 1.1175x; 1.1175x over previous
//
#include <hip/hip_runtime.h>
#include <hip/hip_bf16.h>
#include <math.h>

#define BB 2
#define CC 256
#define CMID 16
#define HH 96
#define WW 96
#define HWSZ (HH*WW)
#define SH 48
#define SHSZ (SH*SH)
#define MMK 7
#define HO 90
#define WO 90
#define NPATCH (HO*WO)
#define NSITE (BB*CMID*NPATCH)
#define NPIX (BB*HWSZ)          // 18432 projection pixels
#define QBLK 288                // pixel blocks of 64 (NPIX/64)
#define HPS 29                  // hp LDS stride (28 + 1 pad)
#define CSW 22                  // csn tile width

typedef __hip_bfloat16 bf16;

__device__ __forceinline__ float ldf(const bf16* p){ return __bfloat162float(*p); }
__device__ __forceinline__ float ldf(const float* p){ return *p; }
__device__ __forceinline__ void stf(bf16* p, float v){ *p = __float2bfloat16(v); }
__device__ __forceinline__ void stf(float* p, float v){ *p = v; }

// ---------------- dtype detect: 1 = inputs are fp32, 0 = inputs are bf16.
// LOAD-BEARING (13-round evidence: every build without this runtime dispatch
// NaN'd; every build with it passed). Do not remove.
__global__ void k_detect(const unsigned int* __restrict__ words, int* __restrict__ flag) {
    __shared__ int cnt;
    if (threadIdx.x == 0) cnt = 0;
    __syncthreads();
    const uint4* p = (const uint4*)words;
    uint4 v = p[threadIdx.x];
    int c = 0;
    unsigned int w[4] = {v.x, v.y, v.z, v.w};
#pragma unroll
    for (int k = 0; k < 4; k++) {
        unsigned int h0 = w[k] & 0xFFFFu, h1 = w[k] >> 16;
        if (((h0 >> 7) & 0xFFu) == 0xFFu) c++;
        if (((h1 >> 7) & 0xFFu) == 0xFFu) c++;
    }
    if (c) atomicAdd(&cnt, c);
    __syncthreads();
    if (threadIdx.x == 0) *flag = (cnt > 0) ? 1 : 0;
}

// ---------------- bilinear coords (exact dyadic arithmetic, reference order)
struct BiC { int r0, r1; float wr; };
__device__ __forceinline__ BiC bic(int y) {
    float sy = fminf(fmaxf((y + 0.5f) * 0.5f - 0.5f, 0.f), 47.f);
    BiC b; b.r0 = (int)sy; b.r1 = min(b.r0 + 1, 47); b.wr = sy - (float)b.r0;
    return b;
}
template<typename T>
__device__ __forceinline__ float upsamp(const T* __restrict__ plane, BiC ry, BiC rx) {
    float v00 = ldf(plane + ry.r0 * SH + rx.r0);
    float v01 = ldf(plane + ry.r0 * SH + rx.r1);
    float v10 = ldf(plane + ry.r1 * SH + rx.r0);
    float v11 = ldf(plane + ry.r1 * SH + rx.r1);
    float row0 = v00 * (1.f - ry.wr) + v10 * ry.wr;   // reference order: rows first
    float row1 = v01 * (1.f - ry.wr) + v11 * ry.wr;
    return row0 * (1.f - rx.wr) + row1 * rx.wr;
}

// ---------------- K1: unified projection. One kernel, both halves (low/high),
// both dtypes (uniform runtime branch on *flag — replaces 4 launches, 2 dead).
// 4 waves/block = 4 channel quarters; LDS reduce in the OLD consumer merge
// order ((q0+q1)+q2)+q3 -> bit-identical xl/xh to the previous partial-sum
// scheme, but written MERGED (cuts k_dir_both reads 8->2 streams, k_fold 4->1).
template<typename T>
__device__ __forceinline__ void proj_acc_low(const T* __restrict__ src, int b, int hw,
                                             int c0, const float* __restrict__ wsl,
                                             float* __restrict__ acc) {
    const T* sp = src + (size_t)b * CC * HWSZ + (size_t)c0 * HWSZ + hw;
    for (int c = 0; c < 64; c++) {
        float v = ldf(sp + (size_t)c * HWSZ);
#pragma unroll
        for (int o = 0; o < CMID; o++) acc[o] = fmaf(v, wsl[o * 64 + c], acc[o]);
    }
}
template<typename T>
__device__ __forceinline__ void proj_acc_high(const T* __restrict__ xhigh, int b, int c0,
                                              BiC ry, BiC rx, const float* __restrict__ wsl,
                                              float* __restrict__ acc) {
    const T* sp = xhigh + ((size_t)b * CC + c0) * SHSZ;
    for (int c = 0; c < 64; c++) {
        float v = upsamp(sp + (size_t)c * SHSZ, ry, rx);
#pragma unroll
        for (int o = 0; o < CMID; o++) acc[o] = fmaf(v, wsl[o * 64 + c], acc[o]);
    }
}

__global__ __launch_bounds__(256) void k_proj(const void* __restrict__ xhigh,
                                              const void* __restrict__ xlow,
                                              const void* __restrict__ wlo,
                                              const void* __restrict__ whi,
                                              float* __restrict__ xl,
                                              float* __restrict__ xh,
                                              const int* __restrict__ flag) {
    __shared__ float wsm[4 * CMID * 64];   // 16 KB: per-wave weight slices
    __shared__ float red[4 * CMID * 64];   // 16 KB: cross-wave reduction
    const int isf  = *flag;
    const int half = blockIdx.x / QBLK;    // 0 = low path, 1 = high (upsampled) path
    const int pxb  = blockIdx.x % QBLK;
    const int w = threadIdx.x >> 6, lane = threadIdx.x & 63;
    const int c0 = w * 64;
    const void* wmat = half ? whi : wlo;
    float* wsl = wsm + w * CMID * 64;
    for (int t = lane; t < CMID * 64; t += 64) {
        int o = t >> 6, c = t & 63;
        wsl[t] = isf ? ldf((const float*)wmat + o * CC + c0 + c)
                     : ldf((const bf16*)wmat  + o * CC + c0 + c);
    }
    __syncthreads();
    const int px = pxb * 64 + lane;
    const int b = px / HWSZ, hw = px % HWSZ;
    float acc[CMID];
#pragma unroll
    for (int o = 0; o < CMID; o++) acc[o] = 0.f;
    if (half == 0) {
        if (isf) proj_acc_low<float>((const float*)xlow, b, hw, c0, wsl, acc);
        else     proj_acc_low<bf16 >((const bf16* )xlow, b, hw, c0, wsl, acc);
    } else {
        int x = hw % WW, y = hw / WW;
        BiC ry = bic(y), rx = bic(x);
        if (isf) proj_acc_high<float>((const float*)xhigh, b, c0, ry, rx, wsl, acc);
        else     proj_acc_high<bf16 >((const bf16* )xhigh, b, c0, ry, rx, wsl, acc);
    }
    float* rsl = red + w * CMID * 64;
#pragma unroll
    for (int o = 0; o < CMID; o++) rsl[o * 64 + lane] = acc[o];
    __syncthreads();
    const int og = threadIdx.x >> 6, p2 = threadIdx.x & 63;
    const int px2 = pxb * 64 + p2;
    const int b2 = px2 / HWSZ, hw2 = px2 % HWSZ;
    float* dst = half ? xh : xl;
#pragma unroll
    for (int oo = 0; oo < 4; oo++) {
        int o = og * 4 + oo;
        const float* r0 = red + o * 64 + p2;
        // exact old merge order: ((q0+q1)+q2)+q3
        float s = ((r0[0] + r0[CMID * 64]) + r0[2 * CMID * 64]) + r0[3 * CMID * 64];
        dst[((size_t)b2 * CMID + o) * HWSZ + hw2] = s;
    }
}

// ---------------- row-shared direction: v-pass + sqrt-free argmax.
// Returns the winning integer index bk (no transcendentals here anymore).
// Identical FMA/compare order to the previous version -> identical bk.
__device__ __forceinline__ int dir_from_acol(const float2 (* __restrict__ acol)[WW],
                                             int px) {
    constexpr float TRE[7] = {1.f, 0.6234898019f, -0.2225209340f, -0.9009688679f,
                              -0.9009688679f, -0.2225209340f, 0.6234898019f};
    constexpr float TIM[7] = {0.f, -0.7818314825f, -0.9749279122f, -0.4338837391f,
                              0.4338837391f, 0.9749279122f, 0.7818314825f};
    constexpr float RS[7] = {9.f, 9.f, 4.f, 1.f, 0.f, 1.f, 4.f}; // FS[t]^2

    float best = -1.f;
    int bk = 0;
#pragma unroll
    for (int u = 0; u < 4; u++) {
        float2 a[7];
#pragma unroll
        for (int c = 0; c < 7; c++) a[c] = acol[u][px + c];
#pragma unroll
        for (int v = 0; v < 7; v++) {
            if (u == 0 && v >= 4) continue;  // row-0 conjugates live within the row
            float Fr = 0.f, Fi = 0.f;
#pragma unroll
            for (int c = 0; c < 7; c++) {
                const int t = (v * c) % 7;
                Fr += a[c].x * TRE[t] - a[c].y * TIM[t];
                Fi += a[c].x * TIM[t] + a[c].y * TRE[t];
            }
            float m2 = Fr * Fr + Fi * Fi;
            {
                const int k1 = ((u + 3) % 7) * 7 + ((v + 3) % 7);
                if (k1 != 0) {
                    float s = m2 * (RS[u] + RS[v]);
                    if (s > best || (s == best && k1 < bk)) { best = s; bk = k1; }
                }
            }
            const int u2 = (7 - u) % 7, v2 = (7 - v) % 7;
            if (u2 != u || v2 != v) {
                const int k2 = ((u2 + 3) % 7) * 7 + ((v2 + 3) % 7);
                if (k2 != 0) {
                    float s = m2 * (RS[u2] + RS[v2]);
                    if (s > best || (s == best && k2 < bk)) { best = s; bk = k2; }
                }
            }
        }
    }
    return bk;
}

// Exact (cos theta, sin theta) for the quantized direction index bk.
// theta = atan2(fi,fj) wrapped to [0,pi): fi>0 -> (fj,fi)/r; fi<0 -> (-fj,-fi)/r;
// fi==0 -> (1,0). Replaces atan2f+cosf+sinf; delta vs old path ~1e-7, which
// enters the output only through layer_scale=1e-5 (Δout ~1e-11).
__device__ __forceinline__ float2 dir_cs(int bk) {
    int bi = bk / 7, bj = bk % 7;
    if (bi == 0) return make_float2(1.f, 0.f);
    float fi = (float)(bi <= 3 ? bi : bi - 7);
    float fj = (float)(bj <= 3 ? bj : bj - 7);
    float rinv = rsqrtf(fmaf(fi, fi, fj * fj));
    float sgn = (fi > 0.f) ? 1.f : -1.f;
    return make_float2(sgn * fj * rinv, sgn * fi * rinv);
}

// ---------------- K2: both directions + combine, one patch-row per block.
// Dtype-independent. Now reads MERGED xl/xh (1 stream each, was 4).
// cos/sin of (tl - th) via angle-difference identity on table-exact values.
__global__ __launch_bounds__(128) void k_dir_both(const float* __restrict__ xl,
                                                  const float* __restrict__ xh,
                                                  float2* __restrict__ csn) {
    __shared__ float2 acL[4][WW];
    __shared__ float2 acH[4][WW];
    constexpr float TRE[7] = {1.f, 0.6234898019f, -0.2225209340f, -0.9009688679f,
                              -0.9009688679f, -0.2225209340f, 0.6234898019f};
    constexpr float TIM[7] = {0.f, -0.7818314825f, -0.9749279122f, -0.4338837391f,
                              0.4338837391f, 0.9749279122f, 0.7818314825f};
    const int bcm = blockIdx.x / HO;
    const int py  = blockIdx.x % HO;
    const size_t off = (size_t)bcm * HWSZ;
    int t = threadIdx.x;
    if (t < WW) {
        float colL[7], colH[7];
#pragma unroll
        for (int r = 0; r < 7; r++) {
            size_t a = off + (py + r) * WW + t;
            colL[r] = xl[a];
            colH[r] = xh[a];
        }
#pragma unroll
        for (int u = 0; u < 4; u++) {
            float arL = 0.f, aiL = 0.f, arH = 0.f, aiH = 0.f;
#pragma unroll
            for (int r = 0; r < 7; r++) {
                const int tt = (u * r) % 7;
                arL = fmaf(colL[r], TRE[tt], arL);
                aiL = fmaf(colL[r], TIM[tt], aiL);
                arH = fmaf(colH[r], TRE[tt], arH);
                aiH = fmaf(colH[r], TIM[tt], aiH);
            }
            acL[u][t] = make_float2(arL, aiL);
            acH[u][t] = make_float2(arH, aiH);
        }
    }
    __syncthreads();
    int px = threadIdx.x;
    if (px >= WO) return;
    int kl = dir_from_acol(acL, px);
    int kh = dir_from_acol(acH, px);
    float2 cl = dir_cs(kl);
    float2 ch = dir_cs(kh);
    float cs = cl.x * ch.x + cl.y * ch.y;   // cos(tl - th)
    float sn = cl.y * ch.x - cl.x * ch.y;   // sin(tl - th)
    csn[(size_t)bcm * NPATCH + py * WO + px] = make_float2(cs, sn);
}

// ---------------- K3: unified fold, LDS-tiled, ALL 96x96 pixels.
// Dtype-independent. Now stages hp from the single merged xh.
__global__ __launch_bounds__(256) void k_fold(const float* __restrict__ xh,
                                              const float2* __restrict__ csn,
                                              float* __restrict__ alg) {
    __shared__ float  hps[28 * HPS];        // 3248 B
    __shared__ float2 css[CSW * CSW];       // 3872 B
    const int bcm  = blockIdx.x / 36;
    const int tile = blockIdx.x % 36;
    const int y0 = (tile / 6) * 16;
    const int x0 = (tile % 6) * 16;
    const size_t off = (size_t)bcm * HWSZ;
    const float2* cb = csn + (size_t)bcm * NPATCH;
    for (int t = threadIdx.x; t < 28 * 28; t += 256) {
        int r = t / 28, c = t % 28;
        int gy = y0 - 6 + r, gx = x0 - 6 + c;
        if (gy >= 0 && gy < HH && gx >= 0 && gx < WW)
            hps[r * HPS + c] = xh[off + gy * WW + gx];
    }
    for (int t = threadIdx.x; t < CSW * CSW; t += 256) {
        int r = t / CSW, c = t % CSW;
        int gy = y0 - 6 + r, gx = x0 - 6 + c;
        if (gy >= 0 && gy < HO && gx >= 0 && gx < WO) css[r * CSW + c] = cb[gy * WO + gx];
    }
    __syncthreads();
    const int ly = threadIdx.x / 16, lx = threadIdx.x % 16;
    const int y = y0 + ly, x = x0 + lx;
    float acc = 0.f;
    const int ilo = max(0, y - (HO - 1)), ihi = min(MMK - 1, y);
    const int jlo = max(0, x - (WO - 1)), jhi = min(MMK - 1, x);
    for (int i = ilo; i <= ihi; i++) {
        const int lr = ly + 6 - i;
        float by = -1.f + (2.f * i + 1.f) / 7.f;
        for (int j = jlo; j <= jhi; j++) {
            const int lc = lx + 6 - j;
            float2 cssn = css[lr * CSW + lc];
            float cs = cssn.x, sn = cssn.y;
            float tx = 3.f - cs * 3.f + sn * 3.f;
            float ty = 3.f - sn * 3.f - cs * 3.f;
            float bx = -1.f + (2.f * j + 1.f) / 7.f;
            float gx = cs * bx - sn * by + tx;
            float gy = sn * bx + cs * by + ty;
            float ix = ((gx + 1.f) * 7.f - 1.f) * 0.5f;
            float iy = ((gy + 1.f) * 7.f - 1.f) * 0.5f;
            float fx0 = floorf(ix), fy0 = floorf(iy);
#pragma unroll
            for (int dy = 0; dy < 2; dy++)
#pragma unroll
                for (int dx = 0; dx < 2; dx++) {
                    float xc = fx0 + dx, yc = fy0 + dy;
                    if (xc >= 0.f && xc <= 6.f && yc >= 0.f && yc <= 6.f) {
                        float wgt = (1.f - fabsf(ix - xc)) * (1.f - fabsf(iy - yc));
                        acc = fmaf(hps[(lr + (int)yc) * HPS + (lc + (int)xc)],
                                   wgt, acc);
                    }
                }
        }
    }
    float cy = fminf(fminf((float)(y + 1), 7.f), fminf((float)(HH - y), (float)(HH - MMK + 1)));
    float cx = fminf(fminf((float)(x + 1), 7.f), fminf((float)(WW - x), (float)(WW - MMK + 1)));
    alg[((size_t)bcm * HH + y) * WW + x] = acc / (cy * cx + 1e-8f);
}

// ---------------- K4: out = x_low + ls*(w_recon.aligned) + upsample(x_high)
// Single launch; uniform runtime branch on *flag picks the dtype body.
template<typename T>
__device__ __forceinline__ void final_body(const T* __restrict__ x_low,
                                           const T* __restrict__ x_high,
                                           const float* __restrict__ alg,
                                           const T* __restrict__ wrec,
                                           const T* __restrict__ lscale,
                                           T* __restrict__ out, int idx) {
    int hw = idx % HWSZ;
    int cg = (idx / HWSZ) % (CC / 4);
    int b  = idx / ((CC / 4) * HWSZ);
    int c0 = cg * 4;
    int x = hw % WW, y = hw / WW;
    BiC ry = bic(y), rx = bic(x);
    const float* ap = alg + (size_t)b * CMID * HWSZ + hw;
    float av[CMID];
#pragma unroll
    for (int o = 0; o < CMID; o++) av[o] = ap[o * HWSZ];
    float ls = ldf(lscale);
#pragma unroll
    for (int cc = 0; cc < 4; cc++) {
        int c = c0 + cc;
        float rec = 0.f;
#pragma unroll
        for (int o = 0; o < CMID; o++)
            rec = fmaf(av[o], ldf(wrec + c * CMID + o), rec);
        float upv = upsamp(x_high + ((size_t)b * CC + c) * SHSZ, ry, rx);
        size_t oidx = ((size_t)b * CC + c) * HWSZ + hw;
        float v = ldf(x_low + oidx) + ls * rec;  // reference order: (x_low+ls*rec)+up
        stf(out + oidx, v + upv);
    }
}

__global__ __launch_bounds__(256) void k_final(const void* __restrict__ x_low,
                                               const void* __restrict__ x_high,
                                               const float* __restrict__ alg,
                                               const void* __restrict__ wrec,
                                               const void* __restrict__ lscale,
                                               void* __restrict__ out,
                                               const int* __restrict__ flag) {
    int idx = blockIdx.x * 256 + threadIdx.x;
    if (idx >= BB * (CC / 4) * HWSZ) return;
    if (*flag)
        final_body<float>((const float*)x_low, (const float*)x_high, alg,
                          (const float*)wrec, (const float*)lscale, (float*)out, idx);
    else
        final_body<bf16>((const bf16*)x_low, (const bf16*)x_high, alg,
                         (const bf16*)wrec, (const bf16*)lscale, (bf16*)out, idx);
}

extern "C" void kernel_launch(void* const* d_in, const int* in_sizes, int n_in,
                              void* d_out, int out_size, void* d_ws, size_t ws_size,
                              hipStream_t stream) {
    // ws layout: flag at offset 0; merged xl, xh; csn; alg. ~5.6 MB of 256 MiB.
    const size_t PL = (size_t)BB * CMID * HWSZ;     // 294,912
    int* flag   = (int*)d_ws;
    float* base = (float*)d_ws + 4;
    float* xl = base;
    float* xh = xl + PL;
    float2* csn = (float2*)(xh + PL);               // 259,200 float2
    float* alg  = (float*)(csn + NSITE);

    k_detect<<<1, 1024, 0, stream>>>((const unsigned int*)d_in[0], flag);

    // d_in: [0]=x_high [1]=x_low [2]=w_low [3]=w_high [4]=w_recon [5]=layer_scale
    k_proj<<<2 * QBLK, 256, 0, stream>>>(d_in[0], d_in[1], d_in[2], d_in[3],
                                         xl, xh, flag);

    k_dir_both<<<BB * CMID * HO, 128, 0, stream>>>(xl, xh, csn);

    k_fold<<<BB * CMID * 36, 256, 0, stream>>>(xh, csn, alg);

    const int g4 = (BB * (CC / 4) * HWSZ + 255) / 256;   // 4608 blocks
    k_final<<<g4, 256, 0, stream>>>(d_in[1], d_in[0], alg, d_in[4], d_in[5],
                                    d_out, flag);
}